// Round 5
// baseline (388.956 us; speedup 1.0000x reference)
//
#include <hip/hip_runtime.h>
#include <math.h>

#define BS 32
#define OBJ 128
#define DD 256
#define RR 32
#define EE 64
#define NDEPTH 3

// ---------------------------------------------------------------------------
// Reduce A [32,128,4096] -> Ao [32,128,128], Ar [32,128,32], As [32,128].
// HBM-bound (67 MB); one wave per (b,o) row, coalesced float4. (R1-proven)
// ---------------------------------------------------------------------------
__global__ __launch_bounds__(256) void k_reduceA(const float* __restrict__ A,
                                                 float* __restrict__ Ao,
                                                 float* __restrict__ Ar,
                                                 float* __restrict__ As) {
    int wave = threadIdx.x >> 6;
    int lane = threadIdx.x & 63;
    int row  = blockIdx.x * 4 + wave;
    const float4* src = (const float4*)(A + (size_t)row * (RR * OBJ));
    float* AoRow = Ao + (size_t)row * OBJ;

    float4 arAcc = make_float4(0.f, 0.f, 0.f, 0.f);
#pragma unroll
    for (int it = 0; it < 16; ++it) {
        float4 v = src[it * 64 + lane];
        arAcc.x += v.x; arAcc.y += v.y; arAcc.z += v.z; arAcc.w += v.w;
        float s = v.x + v.y + v.z + v.w;
        s += __shfl_xor(s, 1);
        s += __shfl_xor(s, 2);
        s += __shfl_xor(s, 4);
        if ((lane & 7) == 0) AoRow[it * 8 + (lane >> 3)] = s;
    }
#pragma unroll
    for (int m = 8; m <= 32; m <<= 1) {
        arAcc.x += __shfl_xor(arAcc.x, m);
        arAcc.y += __shfl_xor(arAcc.y, m);
        arAcc.z += __shfl_xor(arAcc.z, m);
        arAcc.w += __shfl_xor(arAcc.w, m);
    }
    if (lane < 8) ((float4*)(Ar + (size_t)row * RR))[lane] = arAcc;
    float t = arAcc.x + arAcc.y + arAcc.z + arAcc.w;
    t += __shfl_xor(t, 1);
    t += __shfl_xor(t, 2);
    t += __shfl_xor(t, 4);
    if (lane == 0) As[row] = t;
}

// ---------------------------------------------------------------------------
// relpart[d][r][f] = sum_e rel_table[r,e] * W2[d][DD+e][f]   (tiny)
// ---------------------------------------------------------------------------
__global__ __launch_bounds__(256) void k_rel(const float* __restrict__ rel,
                                             const float* __restrict__ W2,
                                             float* __restrict__ relpart) {
    int dr = blockIdx.x;
    int d = dr >> 5, r = dr & 31;
    int f = threadIdx.x;
    const float* w  = W2 + (size_t)d * (DD + EE) * DD + (size_t)DD * DD;
    const float* rl = rel + (size_t)r * EE;
    float acc = 0.f;
#pragma unroll 8
    for (int e = 0; e < EE; ++e)
        acc = fmaf(rl[e], w[(size_t)e * DD + f], acc);
    relpart[(size_t)dr * DD + f] = acc;
}

// ---------------------------------------------------------------------------
// K1: C[4096 x 512] = X[4096 x 256] @ [W1[d] | W2a[d]].
// ONE WAVE per block (64 thr), 64x64 tile, 8x8 microtile, BK=32.
// grid (8,64) = 512 blocks = 2 waves/CU. NO barriers (single wave).
// Per kk: 128 SIMD-cyc FMA vs ~4 LDS wave-instrs -> compute-bound (~50% CU).
// A-tile row-major with XOR swizzle (chunk ^= row>>3) so the 8-address
// a-fragment reads spread across all 8 bank-quads. A-frags register-cached
// over 4-kk groups. Double-buffered LDS + register prefetch.
// ---------------------------------------------------------------------------
__global__ __launch_bounds__(64) void k_gemm1(const float* __restrict__ X,
                                              const float* __restrict__ W1,
                                              const float* __restrict__ W2,
                                              const float* __restrict__ b1,
                                              int d,
                                              float* __restrict__ h1,
                                              float* __restrict__ xw) {
    __shared__ float Xs[2][64][32];    // [row][chunk^ (row>>3) swizzled], 8 KB
    __shared__ float Bs[2][32][68];    // [k][n] row-major, pad 68

    const int l  = threadIdx.x;        // 0..63
    const int m0 = blockIdx.y * 64;
    const int n0blk = blockIdx.x * 64; // 0..448 over [W1|W2a]
    const bool isW1 = (n0blk < 256);
    const int ncol0 = isW1 ? n0blk : (n0blk - 256);
    const float* Wbase = isW1 ? (W1 + (size_t)d * DD * DD)
                              : (W2 + (size_t)d * (DD + EE) * DD);

    const int tx = l & 7;              // n: cols tx*8 .. tx*8+7
    const int ty = l >> 3;             // m: rows ty*8 .. ty*8+7

    // staging maps
    const int ar_ = l >> 3, ac_ = l & 7;    // A: rows ar_+8j, k-chunk ac_
    const int br_ = l >> 4, bc_ = l & 15;   // B: rows br_+4j, n-chunk bc_
    const float* aG = X + (size_t)(m0 + ar_) * DD + ac_ * 4;
    const float* bG = Wbase + (size_t)br_ * DD + ncol0 + bc_ * 4;

    float4 pa[8], pb[8];
    float acc[8][8] = {};

    // prologue: K-step 0 -> buf 0
#pragma unroll
    for (int j = 0; j < 8; ++j)
        pa[j] = *(const float4*)(aG + (size_t)(8 * j) * DD);
#pragma unroll
    for (int j = 0; j < 8; ++j)
        pb[j] = *(const float4*)(bG + (size_t)(4 * j) * DD);
#pragma unroll
    for (int j = 0; j < 8; ++j)
        *(float4*)&Xs[0][ar_ + 8 * j][((ac_ ^ j) & 7) * 4] = pa[j];
#pragma unroll
    for (int j = 0; j < 8; ++j)
        *(float4*)&Bs[0][br_ + 4 * j][bc_ * 4] = pb[j];

    for (int t = 0; t < 8; ++t) {
        const int cur = t & 1;
        if (t < 7) {                   // prefetch next K-step into registers
            const int k0n = (t + 1) * 32;
#pragma unroll
            for (int j = 0; j < 8; ++j)
                pa[j] = *(const float4*)(aG + (size_t)(8 * j) * DD + k0n);
#pragma unroll
            for (int j = 0; j < 8; ++j)
                pb[j] = *(const float4*)(bG + (size_t)(k0n + 4 * j) * DD);
        }
#pragma unroll
        for (int g = 0; g < 8; ++g) {  // 8 groups of 4 kk
            float4 af[8];
#pragma unroll
            for (int i = 0; i < 8; ++i)
                af[i] = *(const float4*)&Xs[cur][ty * 8 + i][((g ^ ty) & 7) * 4];
#pragma unroll
            for (int k2 = 0; k2 < 4; ++k2) {
                float4 b0  = *(const float4*)&Bs[cur][g * 4 + k2][tx * 8];
                float4 b1v = *(const float4*)&Bs[cur][g * 4 + k2][tx * 8 + 4];
                const float bb[8] = {b0.x, b0.y, b0.z, b0.w,
                                     b1v.x, b1v.y, b1v.z, b1v.w};
#pragma unroll
                for (int i = 0; i < 8; ++i) {
                    const float av = ((const float*)&af[i])[k2];
#pragma unroll
                    for (int jj = 0; jj < 8; ++jj)
                        acc[i][jj] = fmaf(av, bb[jj], acc[i][jj]);
                }
            }
        }
        if (t < 7) {                   // stage prefetched regs -> other buffer
            const int nxt = cur ^ 1;
#pragma unroll
            for (int j = 0; j < 8; ++j)
                *(float4*)&Xs[nxt][ar_ + 8 * j][((ac_ ^ j) & 7) * 4] = pa[j];
#pragma unroll
            for (int j = 0; j < 8; ++j)
                *(float4*)&Bs[nxt][br_ + 4 * j][bc_ * 4] = pb[j];
        }
    }

    // epilogue
    float4 bias0 = make_float4(0.f, 0.f, 0.f, 0.f);
    float4 bias1 = bias0;
    if (isW1) {
        bias0 = *(const float4*)(b1 + (size_t)d * DD + ncol0 + tx * 8);
        bias1 = *(const float4*)(b1 + (size_t)d * DD + ncol0 + tx * 8 + 4);
    }
    float* dst = isW1 ? h1 : xw;
#pragma unroll
    for (int i = 0; i < 8; ++i) {
        size_t base = (size_t)(m0 + ty * 8 + i) * DD + ncol0 + tx * 8;
        float4 o0, o1;
        o0.x = acc[i][0] + bias0.x; o0.y = acc[i][1] + bias0.y;
        o0.z = acc[i][2] + bias0.z; o0.w = acc[i][3] + bias0.w;
        o1.x = acc[i][4] + bias1.x; o1.y = acc[i][5] + bias1.y;
        o1.z = acc[i][6] + bias1.z; o1.w = acc[i][7] + bias1.w;
        *(float4*)(dst + base) = o0;
        *(float4*)(dst + base + 4) = o1;
    }
}

// ---------------------------------------------------------------------------
// K2 (per batch): agg = Ao[b] @ xw[b] + Ar[b] @ relpart[d]
// out = tanh(agg + As*b2 + h1 + x).  EXACT R1 version (proven, in-place-safe).
// grid (4, 2, 32); 64x64 tile, 4x4 micro, BK=32 (5 K-tiles).
// ---------------------------------------------------------------------------
__global__ __launch_bounds__(256) void k_agg(const float* __restrict__ Ao,
                                             const float* __restrict__ Ar,
                                             const float* __restrict__ As,
                                             const float* __restrict__ relpart,
                                             const float* __restrict__ b2,
                                             int d,
                                             const float* __restrict__ xw,
                                             const float* __restrict__ h1,
                                             const float* __restrict__ xin,
                                             float* __restrict__ xout) {
    __shared__ float Asm[64][33];
    __shared__ float Bs[32][64];

    const int b  = blockIdx.z;
    const int m0 = blockIdx.y * 64;
    const int n0 = blockIdx.x * 64;
    const int tid = threadIdx.x;
    const int tx = tid & 15, ty = tid >> 4;

    const float* AoB = Ao + ((size_t)b * OBJ + m0) * OBJ;
    const float* ArB = Ar + ((size_t)b * OBJ + m0) * RR;
    const float* xwB = xw + (size_t)b * OBJ * DD;
    const float* rp  = relpart + (size_t)d * RR * DD;

    float acc[4][4] = {};

    for (int t = 0; t < 5; ++t) {
        if (t < 4) {
            const int k0 = t * 32;
#pragma unroll
            for (int i = 0; i < 2; ++i) {          // Ao tile 64x32
                int idx = tid + 256 * i;
                int rr = idx >> 3, c4 = idx & 7;
                float4 v = *(const float4*)(AoB + (size_t)rr * OBJ + k0 + c4 * 4);
                Asm[rr][c4 * 4 + 0] = v.x; Asm[rr][c4 * 4 + 1] = v.y;
                Asm[rr][c4 * 4 + 2] = v.z; Asm[rr][c4 * 4 + 3] = v.w;
            }
#pragma unroll
            for (int i = 0; i < 2; ++i) {          // xw tile 32x64
                int idx = tid + 256 * i;
                int rr = idx >> 4, c4 = idx & 15;
                *(float4*)(&Bs[rr][c4 * 4]) =
                    *(const float4*)(xwB + (size_t)(k0 + rr) * DD + n0 + c4 * 4);
            }
        } else {
#pragma unroll
            for (int i = 0; i < 2; ++i) {          // Ar tile 64x32
                int idx = tid + 256 * i;
                int rr = idx >> 3, c4 = idx & 7;
                float4 v = *(const float4*)(ArB + (size_t)rr * RR + c4 * 4);
                Asm[rr][c4 * 4 + 0] = v.x; Asm[rr][c4 * 4 + 1] = v.y;
                Asm[rr][c4 * 4 + 2] = v.z; Asm[rr][c4 * 4 + 3] = v.w;
            }
#pragma unroll
            for (int i = 0; i < 2; ++i) {          // relpart tile 32x64
                int idx = tid + 256 * i;
                int rr = idx >> 4, c4 = idx & 15;
                *(float4*)(&Bs[rr][c4 * 4]) =
                    *(const float4*)(rp + (size_t)rr * DD + n0 + c4 * 4);
            }
        }
        __syncthreads();
#pragma unroll
        for (int kk = 0; kk < 32; ++kk) {
            float a0 = Asm[ty * 4 + 0][kk];
            float a1 = Asm[ty * 4 + 1][kk];
            float a2 = Asm[ty * 4 + 2][kk];
            float a3 = Asm[ty * 4 + 3][kk];
            float4 bv = *(const float4*)(&Bs[kk][tx * 4]);
            acc[0][0] = fmaf(a0, bv.x, acc[0][0]);
            acc[0][1] = fmaf(a0, bv.y, acc[0][1]);
            acc[0][2] = fmaf(a0, bv.z, acc[0][2]);
            acc[0][3] = fmaf(a0, bv.w, acc[0][3]);
            acc[1][0] = fmaf(a1, bv.x, acc[1][0]);
            acc[1][1] = fmaf(a1, bv.y, acc[1][1]);
            acc[1][2] = fmaf(a1, bv.z, acc[1][2]);
            acc[1][3] = fmaf(a1, bv.w, acc[1][3]);
            acc[2][0] = fmaf(a2, bv.x, acc[2][0]);
            acc[2][1] = fmaf(a2, bv.y, acc[2][1]);
            acc[2][2] = fmaf(a2, bv.z, acc[2][2]);
            acc[2][3] = fmaf(a2, bv.w, acc[2][3]);
            acc[3][0] = fmaf(a3, bv.x, acc[3][0]);
            acc[3][1] = fmaf(a3, bv.y, acc[3][1]);
            acc[3][2] = fmaf(a3, bv.z, acc[3][2]);
            acc[3][3] = fmaf(a3, bv.w, acc[3][3]);
        }
        __syncthreads();
    }

    float4 b2v = *(const float4*)(b2 + (size_t)d * DD + n0 + tx * 4);
#pragma unroll
    for (int i = 0; i < 4; ++i) {
        int m = m0 + ty * 4 + i;
        float asv = As[(size_t)b * OBJ + m];
        size_t base = ((size_t)b * OBJ + m) * DD + n0 + tx * 4;
        float4 hv = *(const float4*)(h1 + base);
        float4 xv = *(const float4*)(xin + base);
        float4 o;
        o.x = tanhf(acc[i][0] + asv * b2v.x + hv.x + xv.x);
        o.y = tanhf(acc[i][1] + asv * b2v.y + hv.y + xv.y);
        o.z = tanhf(acc[i][2] + asv * b2v.z + hv.z + xv.z);
        o.w = tanhf(acc[i][3] + asv * b2v.w + hv.w + xv.w);
        *(float4*)(xout + base) = o;
    }
}

// ---------------------------------------------------------------------------
extern "C" void kernel_launch(void* const* d_in, const int* in_sizes, int n_in,
                              void* d_out, int out_size, void* d_ws, size_t ws_size,
                              hipStream_t stream) {
    const float* x    = (const float*)d_in[0];
    const float* A    = (const float*)d_in[1];
    const float* rel  = (const float*)d_in[2];
    const float* W1   = (const float*)d_in[3];
    const float* b1   = (const float*)d_in[4];
    const float* W2   = (const float*)d_in[5];
    const float* b2   = (const float*)d_in[6];
    float* out = (float*)d_out;

    float* Ao      = (float*)d_ws;                       // 32*128*128
    float* Ar      = Ao + (size_t)BS * OBJ * OBJ;        // 32*128*32
    float* As_     = Ar + (size_t)BS * OBJ * RR;         // 32*128
    float* relpart = As_ + (size_t)BS * OBJ;             // 3*32*256
    float* xwbuf   = relpart + (size_t)NDEPTH * RR * DD; // 32*128*256
    float* h1buf   = xwbuf + (size_t)BS * OBJ * DD;      // 32*128*256
    float* xbuf    = h1buf + (size_t)BS * OBJ * DD;      // 32*128*256

    k_reduceA<<<dim3(BS * OBJ / 4), dim3(256), 0, stream>>>(A, Ao, Ar, As_);
    k_rel<<<dim3(NDEPTH * RR), dim3(256), 0, stream>>>(rel, W2, relpart);

    const float* xcur = x;
    for (int d = 0; d < NDEPTH; ++d) {
        float* xnext = (d == NDEPTH - 1) ? out : xbuf;
        k_gemm1<<<dim3(8, 64), dim3(64), 0, stream>>>(xcur, W1, W2, b1, d, h1buf, xwbuf);
        k_agg<<<dim3(4, 2, BS), dim3(256), 0, stream>>>(Ao, Ar, As_, relpart, b2, d,
                                                        xwbuf, h1buf, xcur, xnext);
        xcur = xnext;
    }
}

// Round 6
// 244.312 us; speedup vs baseline: 1.5920x; 1.5920x over previous
//
#include <hip/hip_runtime.h>
#include <math.h>

#define BS 32
#define OBJ 128
#define DD 256
#define RR 32
#define EE 64
#define NDEPTH 3

// async global->LDS DMA, 16B per lane; LDS dest = uniform base + lane*16
#define GLOAD_LDS(gp, lp)                                                     \
    __builtin_amdgcn_global_load_lds(                                         \
        (const __attribute__((address_space(1))) unsigned*)(gp),              \
        (__attribute__((address_space(3))) unsigned*)(lp), 16, 0, 0)

// s_waitcnt imm: vmcnt[3:0]|[15:14], expcnt[6:4], lgkmcnt[11:8]
#define WAIT_VM16() __builtin_amdgcn_s_waitcnt(0x4F70)   // vmcnt(16)
#define WAIT_VM0()  __builtin_amdgcn_s_waitcnt(0x0F70)   // vmcnt(0)

// ---------------------------------------------------------------------------
// Merged: blocks 0..1023 reduce A -> Ao/Ar/As (R1-proven path);
// blocks 1024..1119 compute relpart[d][r][f] = sum_e rel[r,e]*W2[d][DD+e][f].
// One launch instead of two (saves a ~8.5 us dispatch gap).
// ---------------------------------------------------------------------------
__global__ __launch_bounds__(256) void k_prep(const float* __restrict__ A,
                                              const float* __restrict__ rel,
                                              const float* __restrict__ W2,
                                              float* __restrict__ Ao,
                                              float* __restrict__ Ar,
                                              float* __restrict__ As,
                                              float* __restrict__ relpart) {
    if (blockIdx.x < 1024) {
        int wave = threadIdx.x >> 6;
        int lane = threadIdx.x & 63;
        int row  = blockIdx.x * 4 + wave;
        const float4* src = (const float4*)(A + (size_t)row * (RR * OBJ));
        float* AoRow = Ao + (size_t)row * OBJ;

        float4 arAcc = make_float4(0.f, 0.f, 0.f, 0.f);
#pragma unroll
        for (int it = 0; it < 16; ++it) {
            float4 v = src[it * 64 + lane];
            arAcc.x += v.x; arAcc.y += v.y; arAcc.z += v.z; arAcc.w += v.w;
            float s = v.x + v.y + v.z + v.w;
            s += __shfl_xor(s, 1);
            s += __shfl_xor(s, 2);
            s += __shfl_xor(s, 4);
            if ((lane & 7) == 0) AoRow[it * 8 + (lane >> 3)] = s;
        }
#pragma unroll
        for (int m = 8; m <= 32; m <<= 1) {
            arAcc.x += __shfl_xor(arAcc.x, m);
            arAcc.y += __shfl_xor(arAcc.y, m);
            arAcc.z += __shfl_xor(arAcc.z, m);
            arAcc.w += __shfl_xor(arAcc.w, m);
        }
        if (lane < 8) ((float4*)(Ar + (size_t)row * RR))[lane] = arAcc;
        float t = arAcc.x + arAcc.y + arAcc.z + arAcc.w;
        t += __shfl_xor(t, 1);
        t += __shfl_xor(t, 2);
        t += __shfl_xor(t, 4);
        if (lane == 0) As[row] = t;
    } else {
        int dr = blockIdx.x - 1024;    // d*32 + r
        int d = dr >> 5, r = dr & 31;
        int f = threadIdx.x;
        const float* w  = W2 + (size_t)d * (DD + EE) * DD + (size_t)DD * DD;
        const float* rl = rel + (size_t)r * EE;
        float acc = 0.f;
#pragma unroll 8
        for (int e = 0; e < EE; ++e)
            acc = fmaf(rl[e], w[(size_t)e * DD + f], acc);
        relpart[(size_t)dr * DD + f] = acc;
    }
}

// ---------------------------------------------------------------------------
// K1: C[4096 x 512] = X[4096 x 256] @ [W1[d] | W2a[d]].
// ONE WAVE per block (64 thr), 64x64 tile, 8x8 microtile, BK=32,
// grid (8,64)=512 blocks = 2 waves/CU. NO barriers, NO staging registers:
// global_load_lds (16B) DMAs both tiles; double-buffered with explicit
// vmcnt(16) waits so next tile's loads stay in flight during compute.
// A tile XOR-swizzled (phys chunk p of row r holds logical c = p ^ (r>>3))
// which the DMA's lane->(row r=8j+l/8, chunk l%8) mapping realizes by reading
// global chunk (l%8)^j. Inner reads: af = b128 at chunk g^ty (8 distinct
// bank-quads across ty -> conflict-free); B rows unpadded (2-way quad = free).
// R5's spill (VGPR 256, 157 MB scratch writes) is structurally removed.
// ---------------------------------------------------------------------------
__global__ __launch_bounds__(64) void k_gemm1(const float* __restrict__ X,
                                              const float* __restrict__ W1,
                                              const float* __restrict__ W2,
                                              const float* __restrict__ b1,
                                              int d,
                                              float* __restrict__ h1,
                                              float* __restrict__ xw) {
    __shared__ float Xs[2][64][32];    // 16 KB, [row][phys chunk*4]
    __shared__ float Bs[2][32][64];    // 16 KB, [k][n] unpadded (DMA needs it)

    const int l  = threadIdx.x;        // 0..63
    const int m0 = blockIdx.y * 64;
    const int n0blk = blockIdx.x * 64; // 0..448 over [W1|W2a]
    const bool isW1 = (n0blk < 256);
    const int ncol0 = isW1 ? n0blk : (n0blk - 256);
    const float* Wbase = isW1 ? (W1 + (size_t)d * DD * DD)
                              : (W2 + (size_t)d * (DD + EE) * DD);

    const int tx = l & 7;              // n: cols tx*8 .. +7
    const int ty = l >> 3;             // m: rows ty*8 .. +7

    // DMA source maps (lane-dependent)
    const int arow = l >> 3;           // row within 8-row group
    const int acol = l & 7;            // physical chunk
    const int brow = l >> 4;           // row within 4-row group
    const int bcol = l & 15;

    float acc[8][8] = {};

#define ISSUE_TILE(buf, k0)                                                   \
    do {                                                                      \
        _Pragma("unroll")                                                     \
        for (int j = 0; j < 8; ++j) {                                         \
            const float* g = X + (size_t)(m0 + 8 * j + arow) * DD + (k0) +    \
                             (((acol ^ j) & 7) << 2);                         \
            GLOAD_LDS(g, &Xs[buf][8 * j][0]);                                 \
        }                                                                     \
        _Pragma("unroll")                                                     \
        for (int j = 0; j < 8; ++j) {                                         \
            const float* g = Wbase + (size_t)((k0) + 4 * j + brow) * DD +     \
                             ncol0 + (bcol << 2);                             \
            GLOAD_LDS(g, &Bs[buf][4 * j][0]);                                 \
        }                                                                     \
    } while (0)

    ISSUE_TILE(0, 0);

    for (int t = 0; t < 8; ++t) {
        const int cur = t & 1;
        if (t < 7) {
            ISSUE_TILE(cur ^ 1, (t + 1) * 32);
            WAIT_VM16();               // drain cur's 16, keep nxt's in flight
        } else {
            WAIT_VM0();
        }
#pragma unroll
        for (int g = 0; g < 8; ++g) {  // 8 groups of 4 kk
            float4 af[8];
#pragma unroll
            for (int i = 0; i < 8; ++i)
                af[i] = *(const float4*)&Xs[cur][ty * 8 + i][((g ^ ty) & 7) * 4];
#pragma unroll
            for (int k2 = 0; k2 < 4; ++k2) {
                float4 b0  = *(const float4*)&Bs[cur][g * 4 + k2][tx * 8];
                float4 b1v = *(const float4*)&Bs[cur][g * 4 + k2][tx * 8 + 4];
                const float bb[8] = {b0.x, b0.y, b0.z, b0.w,
                                     b1v.x, b1v.y, b1v.z, b1v.w};
#pragma unroll
                for (int i = 0; i < 8; ++i) {
                    const float av = ((const float*)&af[i])[k2];
#pragma unroll
                    for (int jj = 0; jj < 8; ++jj)
                        acc[i][jj] = fmaf(av, bb[jj], acc[i][jj]);
                }
            }
        }
    }
#undef ISSUE_TILE

    // epilogue
    float4 bias0 = make_float4(0.f, 0.f, 0.f, 0.f);
    float4 bias1 = bias0;
    if (isW1) {
        bias0 = *(const float4*)(b1 + (size_t)d * DD + ncol0 + tx * 8);
        bias1 = *(const float4*)(b1 + (size_t)d * DD + ncol0 + tx * 8 + 4);
    }
    float* dst = isW1 ? h1 : xw;
#pragma unroll
    for (int i = 0; i < 8; ++i) {
        size_t base = (size_t)(m0 + ty * 8 + i) * DD + ncol0 + tx * 8;
        float4 o0, o1;
        o0.x = acc[i][0] + bias0.x; o0.y = acc[i][1] + bias0.y;
        o0.z = acc[i][2] + bias0.z; o0.w = acc[i][3] + bias0.w;
        o1.x = acc[i][4] + bias1.x; o1.y = acc[i][5] + bias1.y;
        o1.z = acc[i][6] + bias1.z; o1.w = acc[i][7] + bias1.w;
        *(float4*)(dst + base) = o0;
        *(float4*)(dst + base + 4) = o1;
    }
}

// ---------------------------------------------------------------------------
// K2 (per batch): agg = Ao[b] @ xw[b] + Ar[b] @ relpart[d]
// out = tanh(agg + As*b2 + h1 + x).  EXACT R1 version (proven, in-place-safe).
// grid (4, 2, 32); 64x64 tile, 4x4 micro, BK=32 (5 K-tiles).
// ---------------------------------------------------------------------------
__global__ __launch_bounds__(256) void k_agg(const float* __restrict__ Ao,
                                             const float* __restrict__ Ar,
                                             const float* __restrict__ As,
                                             const float* __restrict__ relpart,
                                             const float* __restrict__ b2,
                                             int d,
                                             const float* __restrict__ xw,
                                             const float* __restrict__ h1,
                                             const float* __restrict__ xin,
                                             float* __restrict__ xout) {
    __shared__ float Asm[64][33];
    __shared__ float Bs[32][64];

    const int b  = blockIdx.z;
    const int m0 = blockIdx.y * 64;
    const int n0 = blockIdx.x * 64;
    const int tid = threadIdx.x;
    const int tx = tid & 15, ty = tid >> 4;

    const float* AoB = Ao + ((size_t)b * OBJ + m0) * OBJ;
    const float* ArB = Ar + ((size_t)b * OBJ + m0) * RR;
    const float* xwB = xw + (size_t)b * OBJ * DD;
    const float* rp  = relpart + (size_t)d * RR * DD;

    float acc[4][4] = {};

    for (int t = 0; t < 5; ++t) {
        if (t < 4) {
            const int k0 = t * 32;
#pragma unroll
            for (int i = 0; i < 2; ++i) {          // Ao tile 64x32
                int idx = tid + 256 * i;
                int rr = idx >> 3, c4 = idx & 7;
                float4 v = *(const float4*)(AoB + (size_t)rr * OBJ + k0 + c4 * 4);
                Asm[rr][c4 * 4 + 0] = v.x; Asm[rr][c4 * 4 + 1] = v.y;
                Asm[rr][c4 * 4 + 2] = v.z; Asm[rr][c4 * 4 + 3] = v.w;
            }
#pragma unroll
            for (int i = 0; i < 2; ++i) {          // xw tile 32x64
                int idx = tid + 256 * i;
                int rr = idx >> 4, c4 = idx & 15;
                *(float4*)(&Bs[rr][c4 * 4]) =
                    *(const float4*)(xwB + (size_t)(k0 + rr) * DD + n0 + c4 * 4);
            }
        } else {
#pragma unroll
            for (int i = 0; i < 2; ++i) {          // Ar tile 64x32
                int idx = tid + 256 * i;
                int rr = idx >> 3, c4 = idx & 7;
                float4 v = *(const float4*)(ArB + (size_t)rr * RR + c4 * 4);
                Asm[rr][c4 * 4 + 0] = v.x; Asm[rr][c4 * 4 + 1] = v.y;
                Asm[rr][c4 * 4 + 2] = v.z; Asm[rr][c4 * 4 + 3] = v.w;
            }
#pragma unroll
            for (int i = 0; i < 2; ++i) {          // relpart tile 32x64
                int idx = tid + 256 * i;
                int rr = idx >> 4, c4 = idx & 15;
                *(float4*)(&Bs[rr][c4 * 4]) =
                    *(const float4*)(rp + (size_t)rr * DD + n0 + c4 * 4);
            }
        }
        __syncthreads();
#pragma unroll
        for (int kk = 0; kk < 32; ++kk) {
            float a0 = Asm[ty * 4 + 0][kk];
            float a1 = Asm[ty * 4 + 1][kk];
            float a2 = Asm[ty * 4 + 2][kk];
            float a3 = Asm[ty * 4 + 3][kk];
            float4 bv = *(const float4*)(&Bs[kk][tx * 4]);
            acc[0][0] = fmaf(a0, bv.x, acc[0][0]);
            acc[0][1] = fmaf(a0, bv.y, acc[0][1]);
            acc[0][2] = fmaf(a0, bv.z, acc[0][2]);
            acc[0][3] = fmaf(a0, bv.w, acc[0][3]);
            acc[1][0] = fmaf(a1, bv.x, acc[1][0]);
            acc[1][1] = fmaf(a1, bv.y, acc[1][1]);
            acc[1][2] = fmaf(a1, bv.z, acc[1][2]);
            acc[1][3] = fmaf(a1, bv.w, acc[1][3]);
            acc[2][0] = fmaf(a2, bv.x, acc[2][0]);
            acc[2][1] = fmaf(a2, bv.y, acc[2][1]);
            acc[2][2] = fmaf(a2, bv.z, acc[2][2]);
            acc[2][3] = fmaf(a2, bv.w, acc[2][3]);
            acc[3][0] = fmaf(a3, bv.x, acc[3][0]);
            acc[3][1] = fmaf(a3, bv.y, acc[3][1]);
            acc[3][2] = fmaf(a3, bv.z, acc[3][2]);
            acc[3][3] = fmaf(a3, bv.w, acc[3][3]);
        }
        __syncthreads();
    }

    float4 b2v = *(const float4*)(b2 + (size_t)d * DD + n0 + tx * 4);
#pragma unroll
    for (int i = 0; i < 4; ++i) {
        int m = m0 + ty * 4 + i;
        float asv = As[(size_t)b * OBJ + m];
        size_t base = ((size_t)b * OBJ + m) * DD + n0 + tx * 4;
        float4 hv = *(const float4*)(h1 + base);
        float4 xv = *(const float4*)(xin + base);
        float4 o;
        o.x = tanhf(acc[i][0] + asv * b2v.x + hv.x + xv.x);
        o.y = tanhf(acc[i][1] + asv * b2v.y + hv.y + xv.y);
        o.z = tanhf(acc[i][2] + asv * b2v.z + hv.z + xv.z);
        o.w = tanhf(acc[i][3] + asv * b2v.w + hv.w + xv.w);
        *(float4*)(xout + base) = o;
    }
}

// ---------------------------------------------------------------------------
extern "C" void kernel_launch(void* const* d_in, const int* in_sizes, int n_in,
                              void* d_out, int out_size, void* d_ws, size_t ws_size,
                              hipStream_t stream) {
    const float* x    = (const float*)d_in[0];
    const float* A    = (const float*)d_in[1];
    const float* rel  = (const float*)d_in[2];
    const float* W1   = (const float*)d_in[3];
    const float* b1   = (const float*)d_in[4];
    const float* W2   = (const float*)d_in[5];
    const float* b2   = (const float*)d_in[6];
    float* out = (float*)d_out;

    float* Ao      = (float*)d_ws;                       // 32*128*128
    float* Ar      = Ao + (size_t)BS * OBJ * OBJ;        // 32*128*32
    float* As_     = Ar + (size_t)BS * OBJ * RR;         // 32*128
    float* relpart = As_ + (size_t)BS * OBJ;             // 3*32*256
    float* xwbuf   = relpart + (size_t)NDEPTH * RR * DD; // 32*128*256
    float* h1buf   = xwbuf + (size_t)BS * OBJ * DD;      // 32*128*256
    float* xbuf    = h1buf + (size_t)BS * OBJ * DD;      // 32*128*256

    k_prep<<<dim3(1024 + NDEPTH * RR), dim3(256), 0, stream>>>(
        A, rel, W2, Ao, Ar, As_, relpart);

    const float* xcur = x;
    for (int d = 0; d < NDEPTH; ++d) {
        float* xnext = (d == NDEPTH - 1) ? out : xbuf;
        k_gemm1<<<dim3(8, 64), dim3(64), 0, stream>>>(xcur, W1, W2, b1, d, h1buf, xwbuf);
        k_agg<<<dim3(4, 2, BS), dim3(256), 0, stream>>>(Ao, Ar, As_, relpart, b2, d,
                                                        xwbuf, h1buf, xcur, xnext);
        xcur = xnext;
    }
}